// Round 20
// baseline (58.390 us; speedup 1.0000x reference)
//
#include <hip/hip_runtime.h>
#include <stdint.h>

typedef unsigned int u32;
typedef unsigned long long u64;
typedef int v4i  __attribute__((ext_vector_type(4)));
typedef int v16i __attribute__((ext_vector_type(16)));

// Binarized MLP via i8 MFMA, LAYER-SPLIT into per-layer kernels (r20).
// r14-r19: every fused structure lands at 39-48us with all pipes <30% --
// the monolithic kernel hides where time goes. Split gives per-layer
// dur/MfmaUtil via rocprof, deletes inter-layer barrier convoys, and moves
// the x-read into a massively-parallel BW-bound pack kernel. Acts pass as
// bit-words in ws (slab-aliased; kernel-boundary coherence is guaranteed).
// Verbatim-proven pieces: weight pack (r10/r15), expandpm (r14), MFMA asm +
// s_nop2 hazard (r13), transposed Ai8 + expand_to (r17/r18), 64x64 wave
// tile kloop (r18), 2-col epilogue C/D map (r14/r18), BN order, Apre, L4 (r15).

#define NB    16384
#define DIN   784
#define HID   512
#define DOUT  10

// ws byte offsets
#define W1OFF 0           // [25 ks][2 kh][512 col][16] i8  (409600 B)
#define W2OFF 409600      // [16][2][512][16]
#define W3OFF 671744      // [16][2][512][16]
#define W4OFF 933888      // [16][2][32 col][16], col>=10 zeroed
#define APOFF 950272      // Apre f32[3][512], ends 956416
#define XPOFF 956416      // Xp u32[16384][26] (1.70 MB); A2b aliases this slab
#define A1OFF 2660352     // A1b u32[16384][16] (1 MB); A3b aliases this slab
                          // total ws = 3,708,928 B

// ---------------- pack: weights->±1 i8 + Apre + x->bits (one dispatch) ----
__global__ void bmlp_pack(const float* __restrict__ x,
                          const float* __restrict__ w1, const float* __restrict__ w2,
                          const float* __restrict__ w3, const float* __restrict__ w4,
                          const float* __restrict__ g1, const float* __restrict__ v1,
                          const float* __restrict__ g2, const float* __restrict__ v2,
                          const float* __restrict__ g3, const float* __restrict__ v3,
                          char* __restrict__ ws)
{
    const int tid = threadIdx.x, lane = tid & 63;
    if (blockIdx.x >= 238) {                  // x bit-pack: 1 wave = 1 row
        int row = (blockIdx.x - 238) * 4 + (tid >> 6);
        const float* xr = x + (size_t)row * DIN;
        u32* Xp = (u32*)(ws + XPOFF);
        float vx[13];
#pragma unroll
        for (int k = 0; k < 13; ++k) {
            int e = k * 64 + lane;
            vx[k] = (e < DIN) ? xr[e] : 1.0f;           // pad -> bit 0
        }
#pragma unroll
        for (int k = 0; k < 13; ++k) {
            u64 bal = __ballot(vx[k] < 0.0f);
            if (lane == 0) {
                Xp[row * 26 + 2 * k]     = (u32)bal;
                Xp[row * 26 + 2 * k + 1] = (u32)(bal >> 32);
            }
        }
        return;
    }
    int tt = blockIdx.x * 256 + tid;          // weight/Apre region (r15 verbatim)
    const float* src; int base, K, dst16; bool zero = false;
    if (tt < 25600) {                         // W1
        int r = tt, ks = r >> 10, khh = (r >> 9) & 1, col = r & 511;
        base = ks * 32 + khh * 16; src = w1 + col * DIN; K = DIN; dst16 = r;
    } else if (tt < 41984) {                  // W2
        int r = tt - 25600, ks = r >> 10, khh = (r >> 9) & 1, col = r & 511;
        base = ks * 32 + khh * 16; src = w2 + col * HID; K = HID; dst16 = W2OFF / 16 + r;
    } else if (tt < 58368) {                  // W3
        int r = tt - 41984, ks = r >> 10, khh = (r >> 9) & 1, col = r & 511;
        base = ks * 32 + khh * 16; src = w3 + col * HID; K = HID; dst16 = W3OFF / 16 + r;
    } else if (tt < 59392) {                  // W4 (32-col padded, 10 real)
        int r = tt - 58368, ks = r >> 6, khh = (r >> 5) & 1, col = r & 31;
        base = ks * 32 + khh * 16; src = w4 + col * HID; K = HID; dst16 = W4OFF / 16 + r;
        zero = (col >= DOUT);
    } else {                                  // Apre (bit-exact BN scale)
        int ai = tt - 59392;
        if (ai < 1536) {
            int ly = ai >> 9, c = ai & 511;
            const float* g = (ly == 0) ? g1 : (ly == 1) ? g2 : g3;
            const float* v = (ly == 0) ? v1 : (ly == 1) ? v2 : v3;
            float eps = (ly == 2) ? 512.0f : 1e-5f;   // EPS3 source bug: 512
            float A = __fmul_rn(g[c], __fdiv_rn(1.0f, __fsqrt_rn(__fadd_rn(v[c], eps))));
            ((float*)(ws + APOFF))[ai] = A;
        }
        return;
    }
    u32 d[4] = {0u, 0u, 0u, 0u};
    if (!zero) {
#pragma unroll
        for (int j = 0; j < 16; ++j) {
            int eg = base + j;
            u32 byte = 0;                     // K-pad -> 0 (kills act-pad +1 bytes)
            if (eg < K) byte = (src[eg] < 0.0f) ? 0xFFu : 0x01u;   // -1 / +1
            d[j >> 2] |= byte << ((j & 3) * 8);
        }
    }
    v4i val; val.x = (int)d[0]; val.y = (int)d[1]; val.z = (int)d[2]; val.w = (int)d[3];
    ((v4i*)ws)[dst16] = val;
}

// ---------------- shared device pieces (r13-r18 proven) ----------------
__device__ __forceinline__ v4i expandpm(u32 sel)    // 16 bits -> 16 ±1 bytes
{
    u32 e0 = (((sel      ) & 15u) * 0x00204081u) & 0x01010101u;
    u32 e1 = (((sel >> 4 ) & 15u) * 0x00204081u) & 0x01010101u;
    u32 e2 = (((sel >> 8 ) & 15u) * 0x00204081u) & 0x01010101u;
    u32 e3 = (((sel >> 12) & 15u) * 0x00204081u) & 0x01010101u;
    v4i r;
    r.x = (int)(0x01010101u + e0 * 254u);
    r.y = (int)(0x01010101u + e1 * 254u);
    r.z = (int)(0x01010101u + e2 * 254u);
    r.w = (int)(0x01010101u + e3 * 254u);
    return r;
}

// s_nop 2: VALU-write -> MFMA-read wait states around opaque inline asm.
__device__ __forceinline__ void mfma(v16i& a, v4i af, v4i bf)
{
    asm("s_nop 2\n\tv_mfma_i32_32x32x32_i8 %0, %1, %2, %0"
        : "+a"(a) : "v"(af), "v"(bf));
}

// Expand one act bit-word into transposed Ai8 [slot][64 rows][16B].
__device__ __forceinline__ void expand_to(char* Ai8, int row, int slotBase, u32 aw)
{
    v4i lo = expandpm(aw & 0xFFFFu);
    v4i hi = expandpm(aw >> 16);
    *(v4i*)(Ai8 + slotBase * 1024 + row * 16) = lo;
    *(v4i*)(Ai8 + slotBase * 1024 + 1024 + row * 16) = hi;
}

// K-loop: 2 A-reads (contiguous b128) + 2 B-loads (global, L2-hot) + 4 MFMA.
template<int NK>
__device__ __forceinline__ void kloopL(const char* A, const char* __restrict__ Wg,
                                       int kh, int arow16, int coloff, v16i acc[2][2])
{
#pragma unroll
    for (int ks = 0; ks < NK; ++ks) {
        int s = 2 * ks + kh;
        const char* ap = A + s * 1024 + arow16;
        v4i af0 = *(const v4i*)(ap);             // rows l31
        v4i af1 = *(const v4i*)(ap + 512);       // rows l31+32
        const v4i* br = (const v4i*)Wg + (size_t)s * 512 + coloff;
        v4i bf0 = br[0], bf1 = br[32];           // cols wv*64+l31, +32
        mfma(acc[0][0], af0, bf0); mfma(acc[0][1], af0, bf1);
        mfma(acc[1][0], af1, bf0); mfma(acc[1][1], af1, bf1);
    }
}

// BN + sign -> ballot -> bit-packed acts to GLOBAL (r18 epilogue, stride 16).
__device__ __forceinline__ void epilogueG(v16i acc[2][2], u32* __restrict__ dstG,
    int row0, const float* __restrict__ b, const float* __restrict__ m,
    const float* __restrict__ be, const float* __restrict__ Ap,
    int lane, int wv)
{
    asm volatile("s_nop 7\ns_nop 7\ns_nop 7"        // MFMA->read fence
        : "+a"(acc[0][0]), "+a"(acc[0][1]), "+a"(acc[1][0]), "+a"(acc[1][1]));
    const int l31 = lane & 31;
    const int rAdd = (lane & 32) >> 3;              // +4 for hi lanes
    float pb[2], pm[2], pe[2], pA[2];
#pragma unroll
    for (int c = 0; c < 2; ++c) {
        int col = wv * 64 + c * 32 + l31;
        pb[c] = b[col]; pm[c] = m[col]; pe[c] = be[col]; pA[c] = Ap[col];
    }
#pragma unroll
    for (int f = 0; f < 2; ++f)
#pragma unroll
        for (int rg = 0; rg < 16; ++rg) {
            int rowMe = f * 32 + (rg & 3) + 8 * (rg >> 2) + rAdd;
#pragma unroll
            for (int c = 0; c < 2; ++c) {
                float xl = __fadd_rn((float)acc[f][c][rg], pb[c]);
                float y  = __fadd_rn(__fmul_rn(__fsub_rn(xl, pm[c]), pA[c]), pe[c]);
                u64 bal = __ballot(y < 0.0f);       // bit=1 <=> -1
                if (!(lane & 31))                   // lanes 0 and 32
                    dstG[(size_t)(row0 + rowMe) * 16 + (wv * 2 + c)] =
                        (u32)(bal >> ((lane >> 5) << 5));
            }
        }
}

#define ACC_INIT() v16i acc[2][2];                                  \
    _Pragma("unroll") for (int f = 0; f < 2; ++f)                   \
    _Pragma("unroll") for (int c = 0; c < 2; ++c)                   \
    _Pragma("unroll") for (int i = 0; i < 16; ++i) acc[f][c][i] = 0

// ---------------- L1: Xp bits -> A1 bits (K=800, two k-chunks) ----------------
__global__ __launch_bounds__(512)
void bmlp_L1(const char* __restrict__ Wg, const u32* __restrict__ Xp,
             u32* __restrict__ dst, const float* __restrict__ Apl,
             const float* __restrict__ b, const float* __restrict__ m,
             const float* __restrict__ be)
{
    __shared__ __align__(16) char Ai8[32 * 1024];
    const int tid = threadIdx.x, lane = tid & 63, wv = tid >> 6;
    const int l31 = lane & 31;
    const int kh = (lane & 32) >> 5;
    const int arow16 = l31 * 16;
    const int row0 = blockIdx.x * 64;
    const int coloff = wv * 64 + l31;

    ACC_INIT();

    for (int i = tid; i < 64 * 13; i += 512) {      // chunk A: words 0..12
        int row = i & 63, w = i >> 6;
        expand_to(Ai8, row, 2 * w, Xp[(size_t)(row0 + row) * 26 + w]);
    }
    __syncthreads();
    kloopL<13>(Ai8, Wg, kh, arow16, coloff, acc);
    __syncthreads();
    for (int i = tid; i < 64 * 12; i += 512) {      // chunk B: words 13..24
        int row = i & 63, w = i >> 6;
        expand_to(Ai8, row, 2 * w, Xp[(size_t)(row0 + row) * 26 + 13 + w]);
    }
    __syncthreads();
    kloopL<12>(Ai8, Wg + 13 * 16384, kh, arow16, coloff, acc);
    epilogueG(acc, dst, row0, b, m, be, Apl, lane, wv);
}

// ---------------- L2/L3: act bits -> act bits (K=512) ----------------
__global__ __launch_bounds__(512)
void bmlp_mid(const char* __restrict__ Wg, const u32* __restrict__ src,
              u32* __restrict__ dst, const float* __restrict__ Apl,
              const float* __restrict__ b, const float* __restrict__ m,
              const float* __restrict__ be)
{
    __shared__ __align__(16) char Ai8[32 * 1024];
    const int tid = threadIdx.x, lane = tid & 63, wv = tid >> 6;
    const int l31 = lane & 31;
    const int kh = (lane & 32) >> 5;
    const int arow16 = l31 * 16;
    const int row0 = blockIdx.x * 64;
    const int coloff = wv * 64 + l31;

    ACC_INIT();

    for (int i = tid; i < 64 * 16; i += 512) {      // 1024 expand tasks
        int row = i & 63, w = i >> 6;
        expand_to(Ai8, row, 2 * w, src[(size_t)(row0 + row) * 16 + w]);
    }
    __syncthreads();
    kloopL<16>(Ai8, Wg, kh, arow16, coloff, acc);
    epilogueG(acc, dst, row0, b, m, be, Apl, lane, wv);
}

// ---------------- L4: act bits -> out (r15 L4, bits from global) ----------------
__global__ __launch_bounds__(64)
void bmlp_L4(const char* __restrict__ W4g, const u32* __restrict__ src,
             const float* __restrict__ b4, float* __restrict__ out)
{
    const int lane = threadIdx.x;
    const int l31 = lane & 31;
    const int kh16 = (lane & 32) >> 1;
    const int kh = kh16 >> 4;
    const int row0 = blockIdx.x * 64;

    v16i a0, a1;
#pragma unroll
    for (int i = 0; i < 16; ++i) { a0[i] = 0; a1[i] = 0; }

#pragma unroll
    for (int ks = 0; ks < 16; ++ks) {
        u32 aw0 = src[(size_t)(row0 + l31) * 16 + ks];
        u32 aw1 = src[(size_t)(row0 + l31 + 32) * 16 + ks];
        v4i af0 = expandpm((aw0 >> kh16) & 0xFFFFu);
        v4i af1 = expandpm((aw1 >> kh16) & 0xFFFFu);
        v4i bf = *(const v4i*)(W4g + (size_t)((ks * 2 + kh) * 32 + l31) * 16);
        mfma(a0, af0, bf);
        mfma(a1, af1, bf);
    }
    asm volatile("s_nop 7\ns_nop 7\ns_nop 7" : "+a"(a0), "+a"(a1));
    const int rAdd = (lane & 32) >> 3;
    if (l31 < DOUT) {
        float pb4 = b4[l31];
#pragma unroll
        for (int rg = 0; rg < 16; ++rg) {
            int r0 = (rg & 3) + 8 * (rg >> 2) + rAdd;
            out[(size_t)(row0 + r0) * DOUT + l31]      = __fadd_rn((float)a0[rg], pb4);
            out[(size_t)(row0 + 32 + r0) * DOUT + l31] = __fadd_rn((float)a1[rg], pb4);
        }
    }
}

extern "C" void kernel_launch(void* const* d_in, const int* in_sizes, int n_in,
                              void* d_out, int out_size, void* d_ws, size_t ws_size,
                              hipStream_t stream)
{
    const float* x   = (const float*)d_in[0];
    const float* w1  = (const float*)d_in[1];
    const float* b1  = (const float*)d_in[2];
    const float* g1  = (const float*)d_in[3];
    const float* be1 = (const float*)d_in[4];
    const float* m1  = (const float*)d_in[5];
    const float* v1  = (const float*)d_in[6];
    const float* w2  = (const float*)d_in[7];
    const float* b2  = (const float*)d_in[8];
    const float* g2  = (const float*)d_in[9];
    const float* be2 = (const float*)d_in[10];
    const float* m2  = (const float*)d_in[11];
    const float* v2  = (const float*)d_in[12];
    const float* w3  = (const float*)d_in[13];
    const float* b3  = (const float*)d_in[14];
    const float* g3  = (const float*)d_in[15];
    const float* be3 = (const float*)d_in[16];
    const float* m3  = (const float*)d_in[17];
    const float* v3  = (const float*)d_in[18];
    const float* w4  = (const float*)d_in[19];
    const float* b4  = (const float*)d_in[20];
    float* out = (float*)d_out;
    char* ws = (char*)d_ws;                 // 3.71 MB used

    const float* Ap = (const float*)(ws + APOFF);
    u32* Xp  = (u32*)(ws + XPOFF);
    u32* A1b = (u32*)(ws + A1OFF);
    u32* A2b = (u32*)(ws + XPOFF);          // aliases Xp (dead after L1)
    u32* A3b = (u32*)(ws + A1OFF);          // aliases A1b (dead after L2)

    // one pack dispatch: 238 weight/Apre blocks + 4096 x-pack blocks
    bmlp_pack<<<dim3(238 + NB / 4), 256, 0, stream>>>(
        x, w1, w2, w3, w4, g1, v1, g2, v2, g3, v3, ws);

    bmlp_L1<<<dim3(NB / 64), 512, 0, stream>>>(
        ws + W1OFF, Xp, A1b, Ap, b1, m1, be1);
    bmlp_mid<<<dim3(NB / 64), 512, 0, stream>>>(
        ws + W2OFF, A1b, A2b, Ap + 512, b2, m2, be2);
    bmlp_mid<<<dim3(NB / 64), 512, 0, stream>>>(
        ws + W3OFF, A2b, A3b, Ap + 1024, b3, m3, be3);
    bmlp_L4<<<dim3(NB / 64), 64, 0, stream>>>(
        ws + W4OFF, A3b, b4, out);
}

// Round 22
// 49.672 us; speedup vs baseline: 1.1755x; 1.1755x over previous
//
#include <hip/hip_runtime.h>
#include <stdint.h>

typedef unsigned int u32;
typedef unsigned long long u64;
typedef int v4i  __attribute__((ext_vector_type(4)));
typedef int v16i __attribute__((ext_vector_type(16)));

// Binarized MLP via i8 MFMA. r22 = r21 with the compile fix: no LDS pointer
// array (clang rejected the addrspacecast static initializer); buffer bases
// computed arithmetically per use. Design unchanged:
// 2-phase async B staging via __builtin_amdgcn_global_load_lds width=16
// through a 2x32KB LDS double buffer: {issue chunk c+1} {MFMA chunk c}
// {barrier}. Loads issue a full MFMA-phase (~600cy) ahead -- r15-r20 were
// step-serialized (full ds_read+L2 latency exposed per k-step).
// A expanded once into 50-slot transposed Ai8; BN params preloaded; no nops
// on LDS-fed MFMA (VALU-fed hazard only; r10/r11 proved LDS-fed safe).
// Verbatim-proven: pack (r10/r15), expandpm (r14), transposed Ai8 (r17),
// 64x64 kchunk (r18), epilogue C/D map (r18), BN order, Apre, L4 (r18).

#define NB    16384
#define DIN   784
#define HID   512
#define DOUT  10
#define MB    64
#define THR   512

// ws byte offsets (r10 layout)
#define W1OFF 0           // [50 s][512 col][16] i8 = 409600 B
#define W2OFF 409600      // [32 s][512][16] = 262144 B (8 chunks)
#define W3OFF 671744
#define W4OFF 933888      // [32 s][32 col][16]
#define APOFF 950272      // Apre f32[3][512]

// dynamic LDS layout (bytes), total 132096
#define AI8O  0           // Ai8: 50 slots x 1024
#define BUF0O 51200       // B chunk buffers: 2 x 32 KB (buf c = BUF0O + c*32768)
#define A1SO  116736      // A1s u32[64*26]
#define AAO   123392      // AA  u32[64*17]
#define ABO   127744      // AB  u32[64*17]
#define LDSSZ 132096

// ---------------- pack: weights->±1 i8 + Apre (r15 verbatim) ----------------
__global__ void bmlp_pack(const float* __restrict__ w1, const float* __restrict__ w2,
                          const float* __restrict__ w3, const float* __restrict__ w4,
                          const float* __restrict__ g1, const float* __restrict__ v1,
                          const float* __restrict__ g2, const float* __restrict__ v2,
                          const float* __restrict__ g3, const float* __restrict__ v3,
                          char* __restrict__ ws)
{
    int tt = blockIdx.x * 256 + (int)threadIdx.x;
    const float* src; int base, K, dst16; bool zero = false;
    if (tt < 25600) {                         // W1
        int r = tt, ks = r >> 10, khh = (r >> 9) & 1, col = r & 511;
        base = ks * 32 + khh * 16; src = w1 + col * DIN; K = DIN; dst16 = r;
    } else if (tt < 41984) {                  // W2
        int r = tt - 25600, ks = r >> 10, khh = (r >> 9) & 1, col = r & 511;
        base = ks * 32 + khh * 16; src = w2 + col * HID; K = HID; dst16 = W2OFF / 16 + r;
    } else if (tt < 58368) {                  // W3
        int r = tt - 41984, ks = r >> 10, khh = (r >> 9) & 1, col = r & 511;
        base = ks * 32 + khh * 16; src = w3 + col * HID; K = HID; dst16 = W3OFF / 16 + r;
    } else if (tt < 59392) {                  // W4 (32-col padded, 10 real)
        int r = tt - 58368, ks = r >> 6, khh = (r >> 5) & 1, col = r & 31;
        base = ks * 32 + khh * 16; src = w4 + col * HID; K = HID; dst16 = W4OFF / 16 + r;
        zero = (col >= DOUT);
    } else {                                  // Apre (bit-exact BN scale)
        int ai = tt - 59392;
        if (ai < 1536) {
            int ly = ai >> 9, c = ai & 511;
            const float* g = (ly == 0) ? g1 : (ly == 1) ? g2 : g3;
            const float* v = (ly == 0) ? v1 : (ly == 1) ? v2 : v3;
            float eps = (ly == 2) ? 512.0f : 1e-5f;   // EPS3 source bug: 512
            float A = __fmul_rn(g[c], __fdiv_rn(1.0f, __fsqrt_rn(__fadd_rn(v[c], eps))));
            ((float*)(ws + APOFF))[ai] = A;
        }
        return;
    }
    u32 d[4] = {0u, 0u, 0u, 0u};
    if (!zero) {
#pragma unroll
        for (int j = 0; j < 16; ++j) {
            int eg = base + j;
            u32 byte = 0;                     // K-pad -> 0
            if (eg < K) byte = (src[eg] < 0.0f) ? 0xFFu : 0x01u;   // -1 / +1
            d[j >> 2] |= byte << ((j & 3) * 8);
        }
    }
    v4i val; val.x = (int)d[0]; val.y = (int)d[1]; val.z = (int)d[2]; val.w = (int)d[3];
    ((v4i*)ws)[dst16] = val;
}

// ---------------- device helpers ----------------
__device__ __forceinline__ v4i expandpm(u32 sel)    // 16 bits -> 16 ±1 bytes
{
    u32 e0 = (((sel      ) & 15u) * 0x00204081u) & 0x01010101u;
    u32 e1 = (((sel >> 4 ) & 15u) * 0x00204081u) & 0x01010101u;
    u32 e2 = (((sel >> 8 ) & 15u) * 0x00204081u) & 0x01010101u;
    u32 e3 = (((sel >> 12) & 15u) * 0x00204081u) & 0x01010101u;
    v4i r;
    r.x = (int)(0x01010101u + e0 * 254u);
    r.y = (int)(0x01010101u + e1 * 254u);
    r.z = (int)(0x01010101u + e2 * 254u);
    r.w = (int)(0x01010101u + e3 * 254u);
    return r;
}

// LDS-fed MFMA: no VALU->MFMA hazard (r10/r11 proven safe without nops)
__device__ __forceinline__ void mfma(v16i& a, v4i af, v4i bf)
{
    asm("v_mfma_i32_32x32x32_i8 %0, %1, %2, %0" : "+a"(a) : "v"(af), "v"(bf));
}
// VALU-fed MFMA (L4's expandpm af): s_nop 2 covers manual wait states (r13)
__device__ __forceinline__ void mfma_v(v16i& a, v4i af, v4i bf)
{
    asm("s_nop 2\n\tv_mfma_i32_32x32x32_i8 %0, %1, %2, %0"
        : "+a"(a) : "v"(af), "v"(bf));
}

// async global->LDS, 16B per lane (dest = wave-uniform base + lane*16)
__device__ __forceinline__ void gload_lds16(const char* g, char* l)
{
    __builtin_amdgcn_global_load_lds(
        (const __attribute__((address_space(1))) void*)g,
        (__attribute__((address_space(3))) void*)l, 16, 0, 0);
}

// stage nseg 1KB segments of a B chunk; wave wv takes segs wv, wv+8, ...
__device__ __forceinline__ void stage(const char* __restrict__ g, char* l,
                                      int wv, int lane, int nseg)
{
#pragma unroll
    for (int i = 0; i < 4; ++i) {
        int seg = wv + 8 * i;                 // wave-uniform
        if (seg < nseg)
            gload_lds16(g + seg * 1024 + lane * 16, l + seg * 1024);
    }
}

// expand one act bit-word into transposed Ai8 slots 2w,2w+1 (r17 proven)
__device__ __forceinline__ void expand_to(char* Ai8, int row, int slotBase, u32 aw)
{
    v4i lo = expandpm(aw & 0xFFFFu);
    v4i hi = expandpm(aw >> 16);
    *(v4i*)(Ai8 + slotBase * 1024 + row * 16) = lo;
    *(v4i*)(Ai8 + slotBase * 1024 + 1024 + row * 16) = hi;
}

// MFMA one staged chunk: NKS ks-steps; A from Ai8 slot 2t+kh, B from buf
// slice (2*lt+kh). 4 MFMA / ks (r18's 64x64 wave tile, proven).
template<int NKS>
__device__ __forceinline__ void kchunk(const char* Ai8, const char* bufc,
                                       int t0, int kh, int arow16, int colb,
                                       v16i acc[2][2])
{
#pragma unroll
    for (int lt = 0; lt < NKS; ++lt) {
        int t = t0 + lt;
        const char* ap = Ai8 + (2 * t + kh) * 1024 + arow16;
        v4i af0 = *(const v4i*)(ap);             // rows l31
        v4i af1 = *(const v4i*)(ap + 512);       // rows l31+32
        const char* bp = bufc + (2 * lt + kh) * 8192 + colb;
        v4i bf0 = *(const v4i*)(bp);             // cols wv*64+l31
        v4i bf1 = *(const v4i*)(bp + 512);       // +32
        mfma(acc[0][0], af0, bf0); mfma(acc[0][1], af0, bf1);
        mfma(acc[1][0], af1, bf0); mfma(acc[1][1], af1, bf1);
    }
}

// BN + sign -> ballot -> bit-packed acts (r18 epilogue, params preloaded)
__device__ __forceinline__ void epilogue(v16i acc[2][2], u32* dst,
    const float* pb, const float* pm, const float* pe, const float* pA,
    int lane, int wv)
{
    asm volatile("s_nop 7\ns_nop 7\ns_nop 7"        // MFMA->read fence
        : "+a"(acc[0][0]), "+a"(acc[0][1]), "+a"(acc[1][0]), "+a"(acc[1][1]));
    const int rAdd = (lane & 32) >> 3;              // +4 for hi lanes
#pragma unroll
    for (int f = 0; f < 2; ++f)
#pragma unroll
        for (int rg = 0; rg < 16; ++rg) {
            int rowMe = f * 32 + (rg & 3) + 8 * (rg >> 2) + rAdd;
#pragma unroll
            for (int c = 0; c < 2; ++c) {
                float xl = __fadd_rn((float)acc[f][c][rg], pb[c]);
                float y  = __fadd_rn(__fmul_rn(__fsub_rn(xl, pm[c]), pA[c]), pe[c]);
                u64 bal = __ballot(y < 0.0f);       // bit=1 <=> -1
                if (!(lane & 31))                   // lanes 0 and 32
                    dst[rowMe * 17 + (wv * 2 + c)] = (u32)(bal >> ((lane >> 5) << 5));
                acc[f][c][rg] = 0;
            }
        }
}

__global__ __launch_bounds__(THR)
void bmlp_fused(const float* __restrict__ x, const char* __restrict__ ws,
                const float* __restrict__ b1, const float* __restrict__ m1, const float* __restrict__ be1,
                const float* __restrict__ b2, const float* __restrict__ m2, const float* __restrict__ be2,
                const float* __restrict__ b3, const float* __restrict__ m3, const float* __restrict__ be3,
                const float* __restrict__ b4, float* __restrict__ out)
{
    extern __shared__ __align__(16) char smem[];
    char* Ai8 = smem + AI8O;
    u32* A1s = (u32*)(smem + A1SO);
    u32* AA  = (u32*)(smem + AAO);
    u32* AB  = (u32*)(smem + ABO);

    const int tid = threadIdx.x, lane = tid & 63, wv = tid >> 6;   // wv 0..7
    const int l31 = lane & 31;
    const int kh16 = (lane & 32) >> 1;
    const int kh = kh16 >> 4;
    const int arow16 = l31 * 16;
    const int colb = (wv * 64 + l31) * 16;
    const int row0 = blockIdx.x * MB;
    const float* Ap = (const float*)(ws + APOFF);
    const char* W1g = ws + W1OFF;
    const char* W2g = ws + W2OFF;
    const char* W3g = ws + W3OFF;

    // issue W1 chunk0 immediately (lands during xpack)
    stage(W1g, smem + BUF0O, wv, lane, 32);

    // preload BN params (kills in-epilogue global loads)
    float b1p[2], m1p[2], e1p[2], A1p[2];
    float b2p[2], m2p[2], e2p[2], A2p[2];
    float b3p[2], m3p[2], e3p[2], A3p[2];
#pragma unroll
    for (int c = 0; c < 2; ++c) {
        int col = wv * 64 + c * 32 + l31;
        b1p[c] = b1[col]; m1p[c] = m1[col]; e1p[c] = be1[col]; A1p[c] = Ap[col];
        b2p[c] = b2[col]; m2p[c] = m2[col]; e2p[c] = be2[col]; A2p[c] = Ap[512 + col];
        b3p[c] = b3[col]; m3p[c] = m3[col]; e3p[c] = be3[col]; A3p[c] = Ap[1024 + col];
    }

    // inline x-pack: wave wv packs rows [8wv,8wv+8) (13-wide ILP, r15-proven)
#pragma unroll 1
    for (int r = 0; r < 8; ++r) {
        const int row = wv * 8 + r;
        const float* xr = x + (size_t)(row0 + row) * DIN;
        float vx[13];
#pragma unroll
        for (int k = 0; k < 13; ++k) {
            int e = k * 64 + lane;
            vx[k] = (e < DIN) ? xr[e] : 1.0f;       // pad -> bit 0
        }
#pragma unroll
        for (int k = 0; k < 13; ++k) {
            u64 bal = __ballot(vx[k] < 0.0f);
            if (lane == 0) {
                A1s[row * 26 + 2 * k]     = (u32)bal;
                A1s[row * 26 + 2 * k + 1] = (u32)(bal >> 32);
            }
        }
    }
    __syncthreads();                                 // xpack + chunk0 done

    // expand all 25 L1 act words -> Ai8 slots 0..49 (1600 tasks)
    for (int i = tid; i < 64 * 25; i += THR) {
        int row = i & 63, w = i >> 6;
        expand_to(Ai8, row, 2 * w, A1s[row * 26 + w]);
    }
    __syncthreads();

    v16i acc[2][2];
#pragma unroll
    for (int f = 0; f < 2; ++f)
#pragma unroll
        for (int c = 0; c < 2; ++c)
#pragma unroll
            for (int i = 0; i < 16; ++i) acc[f][c][i] = 0;

    int cur = 0;
    // ---- L1: 12 full chunks (ks 0..23) + final half chunk (ks 24) ----
#pragma unroll 1
    for (int c = 0; c < 12; ++c) {
        stage(W1g + (c + 1) * 32768, smem + BUF0O + (cur ^ 1) * 32768,
              wv, lane, (c == 11) ? 16 : 32);
        kchunk<2>(Ai8, smem + BUF0O + cur * 32768, 2 * c, kh, arow16, colb, acc);
        __syncthreads();
        cur ^= 1;
    }
    stage(W2g, smem + BUF0O + (cur ^ 1) * 32768, wv, lane, 32);   // W2 chunk0
    kchunk<1>(Ai8, smem + BUF0O + cur * 32768, 24, kh, arow16, colb, acc);
    __syncthreads();
    cur ^= 1;                                        // buf[cur] = W2 c0
    epilogue(acc, AA, b1p, m1p, e1p, A1p, lane, wv);
    __syncthreads();

    // ---- L2 ----
    for (int i = tid; i < 64 * 16; i += THR) {
        int row = i & 63, w = i >> 6;
        expand_to(Ai8, row, 2 * w, AA[row * 17 + w]);
    }
    __syncthreads();
#pragma unroll 1
    for (int c = 0; c < 8; ++c) {
        if (c < 7) stage(W2g + (c + 1) * 32768, smem + BUF0O + (cur ^ 1) * 32768, wv, lane, 32);
        else       stage(W3g, smem + BUF0O + (cur ^ 1) * 32768, wv, lane, 32);  // W3 c0
        kchunk<2>(Ai8, smem + BUF0O + cur * 32768, 2 * c, kh, arow16, colb, acc);
        __syncthreads();
        cur ^= 1;
    }
    epilogue(acc, AB, b2p, m2p, e2p, A2p, lane, wv);
    __syncthreads();

    // ---- L3 (eps=512 folded into Apre) ----
    for (int i = tid; i < 64 * 16; i += THR) {
        int row = i & 63, w = i >> 6;
        expand_to(Ai8, row, 2 * w, AB[row * 17 + w]);
    }
    __syncthreads();
#pragma unroll 1
    for (int c = 0; c < 8; ++c) {
        if (c < 7) stage(W3g + (c + 1) * 32768, smem + BUF0O + (cur ^ 1) * 32768, wv, lane, 32);
        kchunk<2>(Ai8, smem + BUF0O + cur * 32768, 2 * c, kh, arow16, colb, acc);
        __syncthreads();
        cur ^= 1;
    }
    epilogue(acc, AA, b3p, m3p, e3p, A3p, lane, wv);
    __syncthreads();                                 // AA complete before L4

    // ---- L4: wave 0 only; out = dot + b4 (r18 verbatim, VALU-fed MFMA) ----
    if (wv == 0) {
#pragma unroll
        for (int ks = 0; ks < 16; ++ks) {
            u32 aw0 = AA[l31 * 17 + ks], aw1 = AA[(l31 + 32) * 17 + ks];
            v4i af0 = expandpm((aw0 >> kh16) & 0xFFFFu);
            v4i af1 = expandpm((aw1 >> kh16) & 0xFFFFu);
            v4i bf = *(const v4i*)(ws + W4OFF + (size_t)((ks * 2 + kh) * 32 + l31) * 16);
            mfma_v(acc[0][0], af0, bf);
            mfma_v(acc[1][0], af1, bf);
        }
        asm volatile("s_nop 7\ns_nop 7\ns_nop 7" : "+a"(acc[0][0]), "+a"(acc[1][0]));
        const int rAdd = (lane & 32) >> 3;
        if (l31 < DOUT) {
            float pb4 = b4[l31];
#pragma unroll
            for (int f = 0; f < 2; ++f)
#pragma unroll
                for (int rg = 0; rg < 16; ++rg) {
                    int rowE = f * 32 + (rg & 3) + 8 * (rg >> 2) + rAdd;
                    float dv = (f == 0) ? (float)acc[0][0][rg] : (float)acc[1][0][rg];
                    out[(size_t)(row0 + rowE) * DOUT + l31] = __fadd_rn(dv, pb4);
                }
        }
    }
}

extern "C" void kernel_launch(void* const* d_in, const int* in_sizes, int n_in,
                              void* d_out, int out_size, void* d_ws, size_t ws_size,
                              hipStream_t stream)
{
    const float* x   = (const float*)d_in[0];
    const float* w1  = (const float*)d_in[1];
    const float* b1  = (const float*)d_in[2];
    const float* g1  = (const float*)d_in[3];
    const float* be1 = (const float*)d_in[4];
    const float* m1  = (const float*)d_in[5];
    const float* v1  = (const float*)d_in[6];
    const float* w2  = (const float*)d_in[7];
    const float* b2  = (const float*)d_in[8];
    const float* g2  = (const float*)d_in[9];
    const float* be2 = (const float*)d_in[10];
    const float* m2  = (const float*)d_in[11];
    const float* v2  = (const float*)d_in[12];
    const float* w3  = (const float*)d_in[13];
    const float* b3  = (const float*)d_in[14];
    const float* g3  = (const float*)d_in[15];
    const float* be3 = (const float*)d_in[16];
    const float* m3  = (const float*)d_in[17];
    const float* v3  = (const float*)d_in[18];
    const float* w4  = (const float*)d_in[19];
    const float* b4  = (const float*)d_in[20];
    float* out = (float*)d_out;
    char* ws = (char*)d_ws;                 // ~956 KB used

    bmlp_pack<<<dim3(238), 256, 0, stream>>>(
        w1, w2, w3, w4, g1, v1, g2, v2, g3, v3, ws);

    bmlp_fused<<<dim3(NB / MB), THR, LDSSZ, stream>>>(
        x, ws,
        b1, m1, be1,
        b2, m2, be2,
        b3, m3, be3,
        b4, out);
}

// Round 23
// 44.884 us; speedup vs baseline: 1.3009x; 1.1067x over previous
//
#include <hip/hip_runtime.h>
#include <stdint.h>

typedef unsigned int u32;
typedef unsigned long long u64;
typedef int v4i  __attribute__((ext_vector_type(4)));
typedef int v16i __attribute__((ext_vector_type(16)));

// Binarized MLP via i8 MFMA. r23: proper T3+T4 counted-vmcnt pipeline.
// r22's __syncthreads per chunk lowered to s_waitcnt vmcnt(0)+barrier,
// draining the just-issued prefetch -> every phase exposed ~500cy L2
// latency. Now: flat 57-chunk schedule (W1|W2|W3 contiguous: base =
// ws + g*16384), 4x16KB LDS buffers, stage 3 chunks ahead, per phase
//   stage(g+3); s_waitcnt vmcnt(6); s_barrier; 4x MFMA; s_barrier;
// vmcnt(6) waits ONLY for chunk g's 2 loads (6 newer stay in flight,
// 3-phase ~500cy slack each). Raw barriers + compiler memory fences
// (rule #18: prevent LDS-read hoisting). Tail: vmcnt(4)/(2)/(0).
// Buffer race audit: stage(g+3) writes buf[(g-1)&3], whose readers all
// passed phase g-1's trailing barrier. Epilogue/expand phases issue no
// VMEM so vmcnt counting stays exact across layer boundaries.
// Verbatim-proven: pack (r10/r15), expandpm (r14), transposed Ai8 (r17),
// 64x64 MFMA mapping (r18), epilogue C/D map (r18), BN order, Apre, L4.

#define NB    16384
#define DIN   784
#define HID   512
#define DOUT  10
#define MB    64
#define THR   512

// ws byte offsets: W1|W2|W3 contiguous 16KB chunks 0..56, then W4, Apre
#define W1OFF 0           // chunks 0..24  (409600 B)
#define W2OFF 409600      // chunks 25..40
#define W3OFF 671744      // chunks 41..56
#define W4OFF 933888      // [32 s][32 col][16]
#define APOFF 950272      // Apre f32[3][512]
#define NCH   57

// dynamic LDS layout (bytes), total 132096
#define AI8O  0           // Ai8: 50 slots x 1024
#define BUFO  51200       // 4 x 16KB chunk buffers
#define A1SO  116736      // A1s u32[64*26]
#define AAO   123392      // AA  u32[64*17]
#define ABO   127744      // AB  u32[64*17]
#define LDSSZ 132096

// ---------------- pack: weights->±1 i8 + Apre (r15 verbatim) ----------------
__global__ void bmlp_pack(const float* __restrict__ w1, const float* __restrict__ w2,
                          const float* __restrict__ w3, const float* __restrict__ w4,
                          const float* __restrict__ g1, const float* __restrict__ v1,
                          const float* __restrict__ g2, const float* __restrict__ v2,
                          const float* __restrict__ g3, const float* __restrict__ v3,
                          char* __restrict__ ws)
{
    int tt = blockIdx.x * 256 + (int)threadIdx.x;
    const float* src; int base, K, dst16; bool zero = false;
    if (tt < 25600) {                         // W1
        int r = tt, ks = r >> 10, khh = (r >> 9) & 1, col = r & 511;
        base = ks * 32 + khh * 16; src = w1 + col * DIN; K = DIN; dst16 = r;
    } else if (tt < 41984) {                  // W2
        int r = tt - 25600, ks = r >> 10, khh = (r >> 9) & 1, col = r & 511;
        base = ks * 32 + khh * 16; src = w2 + col * HID; K = HID; dst16 = W2OFF / 16 + r;
    } else if (tt < 58368) {                  // W3
        int r = tt - 41984, ks = r >> 10, khh = (r >> 9) & 1, col = r & 511;
        base = ks * 32 + khh * 16; src = w3 + col * HID; K = HID; dst16 = W3OFF / 16 + r;
    } else if (tt < 59392) {                  // W4 (32-col padded, 10 real)
        int r = tt - 58368, ks = r >> 6, khh = (r >> 5) & 1, col = r & 31;
        base = ks * 32 + khh * 16; src = w4 + col * HID; K = HID; dst16 = W4OFF / 16 + r;
        zero = (col >= DOUT);
    } else {                                  // Apre (bit-exact BN scale)
        int ai = tt - 59392;
        if (ai < 1536) {
            int ly = ai >> 9, c = ai & 511;
            const float* g = (ly == 0) ? g1 : (ly == 1) ? g2 : g3;
            const float* v = (ly == 0) ? v1 : (ly == 1) ? v2 : v3;
            float eps = (ly == 2) ? 512.0f : 1e-5f;   // EPS3 source bug: 512
            float A = __fmul_rn(g[c], __fdiv_rn(1.0f, __fsqrt_rn(__fadd_rn(v[c], eps))));
            ((float*)(ws + APOFF))[ai] = A;
        }
        return;
    }
    u32 d[4] = {0u, 0u, 0u, 0u};
    if (!zero) {
#pragma unroll
        for (int j = 0; j < 16; ++j) {
            int eg = base + j;
            u32 byte = 0;                     // K-pad -> 0
            if (eg < K) byte = (src[eg] < 0.0f) ? 0xFFu : 0x01u;   // -1 / +1
            d[j >> 2] |= byte << ((j & 3) * 8);
        }
    }
    v4i val; val.x = (int)d[0]; val.y = (int)d[1]; val.z = (int)d[2]; val.w = (int)d[3];
    ((v4i*)ws)[dst16] = val;
}

// ---------------- device helpers ----------------
__device__ __forceinline__ v4i expandpm(u32 sel)    // 16 bits -> 16 ±1 bytes
{
    u32 e0 = (((sel      ) & 15u) * 0x00204081u) & 0x01010101u;
    u32 e1 = (((sel >> 4 ) & 15u) * 0x00204081u) & 0x01010101u;
    u32 e2 = (((sel >> 8 ) & 15u) * 0x00204081u) & 0x01010101u;
    u32 e3 = (((sel >> 12) & 15u) * 0x00204081u) & 0x01010101u;
    v4i r;
    r.x = (int)(0x01010101u + e0 * 254u);
    r.y = (int)(0x01010101u + e1 * 254u);
    r.z = (int)(0x01010101u + e2 * 254u);
    r.w = (int)(0x01010101u + e3 * 254u);
    return r;
}

// LDS-fed MFMA: no VALU->MFMA hazard (r10/r11 proven safe without nops)
__device__ __forceinline__ void mfma(v16i& a, v4i af, v4i bf)
{
    asm("v_mfma_i32_32x32x32_i8 %0, %1, %2, %0" : "+a"(a) : "v"(af), "v"(bf));
}
// VALU-fed MFMA (L4's expandpm af): s_nop 2 covers manual wait states (r13)
__device__ __forceinline__ void mfma_v(v16i& a, v4i af, v4i bf)
{
    asm("s_nop 2\n\tv_mfma_i32_32x32x32_i8 %0, %1, %2, %0"
        : "+a"(a) : "v"(af), "v"(bf));
}

// async global->LDS, 16B per lane (dest = wave-uniform base + lane*16)
__device__ __forceinline__ void gload_lds16(const char* g, char* l)
{
    __builtin_amdgcn_global_load_lds(
        (const __attribute__((address_space(1))) void*)g,
        (__attribute__((address_space(3))) void*)l, 16, 0, 0);
}

// stage one 16KB chunk g (if valid): wave wv takes segments 2wv, 2wv+1
__device__ __forceinline__ void stage_chunk(const char* __restrict__ ws,
                                            char* smem, int g, int wv, int lane)
{
    if (g < NCH) {
        const char* src = ws + (size_t)g * 16384 + (wv * 2) * 1024 + lane * 16;
        char* dst = smem + BUFO + (g & 3) * 16384 + (wv * 2) * 1024;
        gload_lds16(src, dst);
        gload_lds16(src + 1024, dst + 1024);
    }
}

// expand one act bit-word into transposed Ai8 slots 2w,2w+1 (r17 proven)
__device__ __forceinline__ void expand_to(char* Ai8, int row, int slotBase, u32 aw)
{
    v4i lo = expandpm(aw & 0xFFFFu);
    v4i hi = expandpm(aw >> 16);
    *(v4i*)(Ai8 + slotBase * 1024 + row * 16) = lo;
    *(v4i*)(Ai8 + slotBase * 1024 + 1024 + row * 16) = hi;
}

// one ks step (4 MFMA) for local chunk ci of the current layer
__device__ __forceinline__ void kphase(const char* Ai8, const char* bufc,
                                       int ci, int kh, int arow16, int colb,
                                       v16i acc[2][2])
{
    const char* ap = Ai8 + (2 * ci + kh) * 1024 + arow16;
    v4i af0 = *(const v4i*)(ap);             // rows l31
    v4i af1 = *(const v4i*)(ap + 512);       // rows l31+32
    const char* bp = bufc + kh * 8192 + colb;
    v4i bf0 = *(const v4i*)(bp);             // cols wv*64+l31
    v4i bf1 = *(const v4i*)(bp + 512);       // +32
    mfma(acc[0][0], af0, bf0); mfma(acc[0][1], af0, bf1);
    mfma(acc[1][0], af1, bf0); mfma(acc[1][1], af1, bf1);
}

// counted-vmcnt pipelined phase (T3+T4). N_ = vmcnt immediate.
#define PHASE(g_, ci_, NSTR)                                         \
    stage_chunk(ws, smem, (g_) + 3, wv, lane);                       \
    asm volatile("s_waitcnt vmcnt(" NSTR ")" ::: "memory");          \
    __builtin_amdgcn_s_barrier();                                    \
    asm volatile("" ::: "memory");                                   \
    kphase(Ai8, smem + BUFO + ((g_) & 3) * 16384, ci_, kh, arow16, colb, acc); \
    asm volatile("" ::: "memory");                                   \
    __builtin_amdgcn_s_barrier();

// BN + sign -> ballot -> bit-packed acts (r18 epilogue, params preloaded)
__device__ __forceinline__ void epilogue(v16i acc[2][2], u32* dst,
    const float* pb, const float* pm, const float* pe, const float* pA,
    int lane, int wv)
{
    asm volatile("s_nop 7\ns_nop 7\ns_nop 7"        // MFMA->read fence
        : "+a"(acc[0][0]), "+a"(acc[0][1]), "+a"(acc[1][0]), "+a"(acc[1][1]));
    const int rAdd = (lane & 32) >> 3;              // +4 for hi lanes
#pragma unroll
    for (int f = 0; f < 2; ++f)
#pragma unroll
        for (int rg = 0; rg < 16; ++rg) {
            int rowMe = f * 32 + (rg & 3) + 8 * (rg >> 2) + rAdd;
#pragma unroll
            for (int c = 0; c < 2; ++c) {
                float xl = __fadd_rn((float)acc[f][c][rg], pb[c]);
                float y  = __fadd_rn(__fmul_rn(__fsub_rn(xl, pm[c]), pA[c]), pe[c]);
                u64 bal = __ballot(y < 0.0f);       // bit=1 <=> -1
                if (!(lane & 31))                   // lanes 0 and 32
                    dst[rowMe * 17 + (wv * 2 + c)] = (u32)(bal >> ((lane >> 5) << 5));
                acc[f][c][rg] = 0;
            }
        }
}

__global__ __launch_bounds__(THR)
void bmlp_fused(const float* __restrict__ x, const char* __restrict__ ws,
                const float* __restrict__ b1, const float* __restrict__ m1, const float* __restrict__ be1,
                const float* __restrict__ b2, const float* __restrict__ m2, const float* __restrict__ be2,
                const float* __restrict__ b3, const float* __restrict__ m3, const float* __restrict__ be3,
                const float* __restrict__ b4, float* __restrict__ out)
{
    extern __shared__ __align__(16) char smem[];
    char* Ai8 = smem + AI8O;
    u32* A1s = (u32*)(smem + A1SO);
    u32* AA  = (u32*)(smem + AAO);
    u32* AB  = (u32*)(smem + ABO);

    const int tid = threadIdx.x, lane = tid & 63, wv = tid >> 6;   // wv 0..7
    const int l31 = lane & 31;
    const int kh16 = (lane & 32) >> 1;
    const int kh = kh16 >> 4;
    const int arow16 = l31 * 16;
    const int colb = (wv * 64 + l31) * 16;
    const int row0 = blockIdx.x * MB;
    const float* Ap = (const float*)(ws + APOFF);

    // prologue: stage chunks 0..2 (6 loads/wave; land during xpack)
    stage_chunk(ws, smem, 0, wv, lane);
    stage_chunk(ws, smem, 1, wv, lane);
    stage_chunk(ws, smem, 2, wv, lane);

    // preload BN params (no global loads inside the pipelined loops)
    float b1p[2], m1p[2], e1p[2], A1p[2];
    float b2p[2], m2p[2], e2p[2], A2p[2];
    float b3p[2], m3p[2], e3p[2], A3p[2];
#pragma unroll
    for (int c = 0; c < 2; ++c) {
        int col = wv * 64 + c * 32 + l31;
        b1p[c] = b1[col]; m1p[c] = m1[col]; e1p[c] = be1[col]; A1p[c] = Ap[col];
        b2p[c] = b2[col]; m2p[c] = m2[col]; e2p[c] = be2[col]; A2p[c] = Ap[512 + col];
        b3p[c] = b3[col]; m3p[c] = m3[col]; e3p[c] = be3[col]; A3p[c] = Ap[1024 + col];
    }

    // inline x-pack: wave wv packs rows [8wv,8wv+8), 2 rows in flight
#pragma unroll 2
    for (int r = 0; r < 8; ++r) {
        const int row = wv * 8 + r;
        const float* xr = x + (size_t)(row0 + row) * DIN;
        float vx[13];
#pragma unroll
        for (int k = 0; k < 13; ++k) {
            int e = k * 64 + lane;
            vx[k] = (e < DIN) ? xr[e] : 1.0f;       // pad -> bit 0
        }
#pragma unroll
        for (int k = 0; k < 13; ++k) {
            u64 bal = __ballot(vx[k] < 0.0f);
            if (lane == 0) {
                A1s[row * 26 + 2 * k]     = (u32)bal;
                A1s[row * 26 + 2 * k + 1] = (u32)(bal >> 32);
            }
        }
    }
    __syncthreads();                                 // xpack visible

    // expand all 25 L1 act words -> Ai8 slots 0..49
    for (int i = tid; i < 64 * 25; i += THR) {
        int row = i & 63, w = i >> 6;
        expand_to(Ai8, row, 2 * w, A1s[row * 26 + w]);
    }
    __syncthreads();

    v16i acc[2][2];
#pragma unroll
    for (int f = 0; f < 2; ++f)
#pragma unroll
        for (int c = 0; c < 2; ++c)
#pragma unroll
            for (int i = 0; i < 16; ++i) acc[f][c][i] = 0;

    // ---- L1: chunks 0..24 ----
#pragma unroll 1
    for (int ci = 0; ci < 25; ++ci) {
        PHASE(ci, ci, "6");
    }
    epilogue(acc, AA, b1p, m1p, e1p, A1p, lane, wv);
    __syncthreads();

    // ---- L2: chunks 25..40 (re-expand acts first; stages keep flying) ----
    for (int i = tid; i < 64 * 16; i += THR) {
        int row = i & 63, w = i >> 6;
        expand_to(Ai8, row, 2 * w, AA[row * 17 + w]);
    }
    __syncthreads();
#pragma unroll 1
    for (int ci = 0; ci < 16; ++ci) {
        PHASE(25 + ci, ci, "6");
    }
    epilogue(acc, AB, b2p, m2p, e2p, A2p, lane, wv);
    __syncthreads();

    // ---- L3: chunks 41..56 (eps=512 folded into Apre) ----
    for (int i = tid; i < 64 * 16; i += THR) {
        int row = i & 63, w = i >> 6;
        expand_to(Ai8, row, 2 * w, AB[row * 17 + w]);
    }
    __syncthreads();
#pragma unroll 1
    for (int ci = 0; ci < 13; ++ci) {
        PHASE(41 + ci, ci, "6");
    }
    // tail: nothing left to stage; drain counted
    { PHASE(54, 13, "4"); }
    { PHASE(55, 14, "2"); }
    { PHASE(56, 15, "0"); }
    epilogue(acc, AA, b3p, m3p, e3p, A3p, lane, wv);
    __syncthreads();                                 // AA complete before L4

    // ---- L4: wave 0 only; out = dot + b4 (r18 verbatim, VALU-fed MFMA) ----
    if (wv == 0) {
#pragma unroll
        for (int ks = 0; ks < 16; ++ks) {
            u32 aw0 = AA[l31 * 17 + ks], aw1 = AA[(l31 + 32) * 17 + ks];
            v4i af0 = expandpm((aw0 >> kh16) & 0xFFFFu);
            v4i af1 = expandpm((aw1 >> kh16) & 0xFFFFu);
            v4i bf = *(const v4i*)(ws + W4OFF + (size_t)((ks * 2 + kh) * 32 + l31) * 16);
            mfma_v(acc[0][0], af0, bf);
            mfma_v(acc[1][0], af1, bf);
        }
        asm volatile("s_nop 7\ns_nop 7\ns_nop 7" : "+a"(acc[0][0]), "+a"(acc[1][0]));
        const int rAdd = (lane & 32) >> 3;
        if (l31 < DOUT) {
            float pb4 = b4[l31];
#pragma unroll
            for (int f = 0; f < 2; ++f)
#pragma unroll
                for (int rg = 0; rg < 16; ++rg) {
                    int rowE = f * 32 + (rg & 3) + 8 * (rg >> 2) + rAdd;
                    float dv = (f == 0) ? (float)acc[0][0][rg] : (float)acc[1][0][rg];
                    out[(size_t)(row0 + rowE) * DOUT + l31] = __fadd_rn(dv, pb4);
                }
        }
    }
}

extern "C" void kernel_launch(void* const* d_in, const int* in_sizes, int n_in,
                              void* d_out, int out_size, void* d_ws, size_t ws_size,
                              hipStream_t stream)
{
    const float* x   = (const float*)d_in[0];
    const float* w1  = (const float*)d_in[1];
    const float* b1  = (const float*)d_in[2];
    const float* g1  = (const float*)d_in[3];
    const float* be1 = (const float*)d_in[4];
    const float* m1  = (const float*)d_in[5];
    const float* v1  = (const float*)d_in[6];
    const float* w2  = (const float*)d_in[7];
    const float* b2  = (const float*)d_in[8];
    const float* g2  = (const float*)d_in[9];
    const float* be2 = (const float*)d_in[10];
    const float* m2  = (const float*)d_in[11];
    const float* v2  = (const float*)d_in[12];
    const float* w3  = (const float*)d_in[13];
    const float* b3  = (const float*)d_in[14];
    const float* g3  = (const float*)d_in[15];
    const float* be3 = (const float*)d_in[16];
    const float* m3  = (const float*)d_in[17];
    const float* v3  = (const float*)d_in[18];
    const float* w4  = (const float*)d_in[19];
    const float* b4  = (const float*)d_in[20];
    float* out = (float*)d_out;
    char* ws = (char*)d_ws;                 // ~956 KB used

    bmlp_pack<<<dim3(238), 256, 0, stream>>>(
        w1, w2, w3, w4, g1, v1, g2, v2, g3, v3, ws);

    bmlp_fused<<<dim3(NB / MB), THR, LDSSZ, stream>>>(
        x, ws,
        b1, m1, be1,
        b2, m2, be2,
        b3, m3, be3,
        b4, out);
}